// Round 6
// baseline (40.325 us; speedup 1.0000x reference)
//
#include <hip/hip_runtime.h>
#include <hip/hip_fp16.h>

// out[t,f,d] = sum_{c=0..9} table[x[t,f,c], d] * w[c],  w[c] = (10-c)/55
// x: (1024,64,10) int32; table: (8000,256) f32; out: (1024,64,256) f32
//
// R5: bottleneck model = VMEM lane-request rate (~4 req/cyc/CU). R2/R4 both
// issued 67M lane-requests -> ~31 us. Fix: maximize bytes per request.
//  - fp16 table, ushort8 (16 B) gathers: 8 dims/lane -> 21M gather reqs
//  - indices as 5x int4 per 2-row pair -> 5.2M reqs
//  - float4 nontemporal stores -> 4.2M reqs (minimum)
// Total ~30M reqs -> main ~14-16 us predicted.
// d-slicing: 8 slices x 32 dims (64 B fp16/row-slice); blockIdx&7 -> XCD;
// per-XCD table working set 8000 x 64 B = 512 KB, L2-resident.
// Fallback to R2 fp32 kernel if ws_size < 4 MB.

#define ROWS_TOTAL  (1024 * 64)
#define TABLE_ROWS  8000
#define TABLE_D     256

typedef float v4f __attribute__((ext_vector_type(4)));
typedef _Float16 h8 __attribute__((ext_vector_type(8)));   // 16 B

// ---- table fp32 -> fp16 (RNE): 512000 quads, 2000 blocks ----
__global__ __launch_bounds__(256)
void cvt_table_f16(const float* __restrict__ t, _Float16* __restrict__ o) {
    const size_t i = (size_t)blockIdx.x * 256 + threadIdx.x;  // one quad each
    v4f v = *reinterpret_cast<const v4f*>(t + i * 4);
    _Float16 r[4];
    r[0] = (_Float16)v.x; r[1] = (_Float16)v.y;
    r[2] = (_Float16)v.z; r[3] = (_Float16)v.w;
    *reinterpret_cast<ushort4*>(o + i * 4) = *reinterpret_cast<ushort4*>(r);
}

// ---- main: 8 slices x 32 dims; 4 lanes/row-slice; 2 rows/thread ----
__global__ __launch_bounds__(256)
void char2vec_f16w(const int* __restrict__ x,
                   const _Float16* __restrict__ tb,
                   float* __restrict__ out) {
    const int slice = blockIdx.x & 7;        // -> XCD (round-robin)
    const int rgrp  = blockIdx.x >> 3;       // row-group of 128 rows
    const int wave  = threadIdx.x >> 6;
    const int lane  = threadIdx.x & 63;
    const int g     = lane >> 2;             // 16 groups of 4 lanes
    const int li    = lane & 3;

    const int row0 = rgrp * 128 + wave * 32 + g * 2;   // even
    const int row1 = row0 + 1;
    const int d    = slice * 32 + li * 8;    // 8 fp16 dims per lane (16 B)

    // 20 indices (2 rows) via 5 int4 loads. row0 even -> row0*40 B is
    // 16-B aligned (80 * k).
    const int4* __restrict__ xi = reinterpret_cast<const int4*>(x + row0 * 10);
    int4 q0 = xi[0], q1 = xi[1], q2 = xi[2], q3 = xi[3], q4 = xi[4];

    int ia[10], ib[10];
    ia[0] = q0.x; ia[1] = q0.y; ia[2] = q0.z; ia[3] = q0.w;
    ia[4] = q1.x; ia[5] = q1.y; ia[6] = q1.z; ia[7] = q1.w;
    ia[8] = q2.x; ia[9] = q2.y;
    ib[0] = q2.z; ib[1] = q2.w;
    ib[2] = q3.x; ib[3] = q3.y; ib[4] = q3.z; ib[5] = q3.w;
    ib[6] = q4.x; ib[7] = q4.y; ib[8] = q4.z; ib[9] = q4.w;

    // 20 independent 16-B gathers, all in flight together.
    h8 va[10], vb[10];
#pragma unroll
    for (int c = 0; c < 10; ++c)
        va[c] = *reinterpret_cast<const h8*>(tb + (size_t)ia[c] * TABLE_D + d);
#pragma unroll
    for (int c = 0; c < 10; ++c)
        vb[c] = *reinterpret_cast<const h8*>(tb + (size_t)ib[c] * TABLE_D + d);

    const float w[10] = {10.f / 55.f, 9.f / 55.f, 8.f / 55.f, 7.f / 55.f,
                         6.f / 55.f,  5.f / 55.f, 4.f / 55.f, 3.f / 55.f,
                         2.f / 55.f,  1.f / 55.f};

    float a0[8] = {0, 0, 0, 0, 0, 0, 0, 0};
    float a1[8] = {0, 0, 0, 0, 0, 0, 0, 0};
#pragma unroll
    for (int c = 0; c < 10; ++c) {
#pragma unroll
        for (int e = 0; e < 8; ++e) {
            a0[e] = fmaf((float)va[c][e], w[c], a0[e]);
            a1[e] = fmaf((float)vb[c][e], w[c], a1[e]);
        }
    }

    v4f s0lo = {a0[0], a0[1], a0[2], a0[3]};
    v4f s0hi = {a0[4], a0[5], a0[6], a0[7]};
    v4f s1lo = {a1[0], a1[1], a1[2], a1[3]};
    v4f s1hi = {a1[4], a1[5], a1[6], a1[7]};

    float* o0 = out + (size_t)row0 * 256 + d;
    float* o1 = out + (size_t)row1 * 256 + d;
    __builtin_nontemporal_store(s0lo, reinterpret_cast<v4f*>(o0));
    __builtin_nontemporal_store(s0hi, reinterpret_cast<v4f*>(o0 + 4));
    __builtin_nontemporal_store(s1lo, reinterpret_cast<v4f*>(o1));
    __builtin_nontemporal_store(s1hi, reinterpret_cast<v4f*>(o1 + 4));
}

// ---- fp32 fallback (R2 kernel) if ws too small ----
__global__ __launch_bounds__(256)
void char2vec_sliced2(const int* __restrict__ x,
                      const float* __restrict__ table,
                      float* __restrict__ out) {
    const int slice = blockIdx.x & 7;
    const int rgrp  = blockIdx.x >> 3;
    const int wave  = threadIdx.x >> 6;
    const int lane  = threadIdx.x & 63;

    const int row0 = rgrp * 64 + wave * 16 + (lane >> 3) * 2;
    const int row1 = row0 + 1;
    const int d    = slice * 32 + (lane & 7) * 4;

    const int2* __restrict__ xa = reinterpret_cast<const int2*>(x + row0 * 10);
    const int2* __restrict__ xb = reinterpret_cast<const int2*>(x + row1 * 10);
    int2 pa[5], pb[5];
#pragma unroll
    for (int i = 0; i < 5; ++i) pa[i] = xa[i];
#pragma unroll
    for (int i = 0; i < 5; ++i) pb[i] = xb[i];

    int ia[10], ib[10];
#pragma unroll
    for (int i = 0; i < 5; ++i) {
        ia[2 * i] = pa[i].x; ia[2 * i + 1] = pa[i].y;
        ib[2 * i] = pb[i].x; ib[2 * i + 1] = pb[i].y;
    }

    v4f va[10], vb[10];
#pragma unroll
    for (int c = 0; c < 10; ++c)
        va[c] = *reinterpret_cast<const v4f*>(table + (size_t)ia[c] * TABLE_D + d);
#pragma unroll
    for (int c = 0; c < 10; ++c)
        vb[c] = *reinterpret_cast<const v4f*>(table + (size_t)ib[c] * TABLE_D + d);

    const float w[10] = {10.f / 55.f, 9.f / 55.f, 8.f / 55.f, 7.f / 55.f,
                         6.f / 55.f,  5.f / 55.f, 4.f / 55.f, 3.f / 55.f,
                         2.f / 55.f,  1.f / 55.f};

    v4f acc0 = (v4f)0.0f, acc1 = (v4f)0.0f;
#pragma unroll
    for (int c = 0; c < 10; ++c) {
        acc0 += va[c] * w[c];
        acc1 += vb[c] * w[c];
    }

    __builtin_nontemporal_store(
        acc0, reinterpret_cast<v4f*>(out + (size_t)row0 * 256 + d));
    __builtin_nontemporal_store(
        acc1, reinterpret_cast<v4f*>(out + (size_t)row1 * 256 + d));
}

extern "C" void kernel_launch(void* const* d_in, const int* in_sizes, int n_in,
                              void* d_out, int out_size, void* d_ws, size_t ws_size,
                              hipStream_t stream) {
    const int*   x     = (const int*)d_in[0];
    const float* table = (const float*)d_in[1];
    float*       out   = (float*)d_out;

    const size_t f16_bytes = (size_t)TABLE_ROWS * TABLE_D * sizeof(_Float16);

    if (ws_size >= f16_bytes) {
        _Float16* tb = (_Float16*)d_ws;
        const int cvt_blocks = (TABLE_ROWS * TABLE_D / 4) / 256;   // 2000
        cvt_table_f16<<<cvt_blocks, 256, 0, stream>>>(table, tb);
        // 128 rows/block, 8 slices: 65536/128 * 8 = 4096 blocks.
        const int blocks = (ROWS_TOTAL / 128) * 8;
        char2vec_f16w<<<blocks, 256, 0, stream>>>(x, tb, out);
    } else {
        const int blocks = (ROWS_TOTAL / 64) * 8;                  // 8192
        char2vec_sliced2<<<blocks, 256, 0, stream>>>(x, table, out);
    }
}

// Round 7
// 39.999 us; speedup vs baseline: 1.0081x; 1.0081x over previous
//
#include <hip/hip_runtime.h>
#include <hip/hip_fp16.h>

// out[t,f,d] = sum_{c=0..9} table[x[t,f,c], d] * w[c],  w[c] = (10-c)/55
// x: (1024,64,10) int32; table: (8000,256) f32; out: (1024,64,256) f32
//
// R6 theory: R1-R5's invariant ~32 us was the SCATTERED WRITE pattern (each
// 1-KB out row split into 4-8 nontemporal 128-256 B segments from different
// XCDs -> ~2 TB/s effective HBM writes). Fix by eliminating d-slicing:
// the fp16 table is 4 MB and fits ENTIRELY in each XCD's 4 MB L2 (replicated
// on demand, 32 MB aggregate). One wave per output row:
//   - lane l owns dims [4l, 4l+4): gathers are 8 B/lane, 512 B contiguous
//     per instr (4 full lines of one table row)
//   - store is ONE fully contiguous 1-KB dwordx4 instr per row
//   - indices: 5 broadcast int2 loads (one line-request each)
// Per-XCD L2 gather volume 40 MB (vs 84 for fp32-sliced); writes nontemporal
// (no-allocate) so the 64-MB write stream can't evict the table from L2.
// fp16 err: rel 2^-11, max|v|~5.5 -> +~0.004 absmax vs threshold 0.03875.
// Fallback to fp32 R2-style sliced kernel if ws_size < 4 MB.

#define ROWS_TOTAL  (1024 * 64)
#define TABLE_ROWS  8000
#define TABLE_D     256

typedef float v4f __attribute__((ext_vector_type(4)));
typedef _Float16 h4 __attribute__((ext_vector_type(4)));   // 8 B

// ---- table fp32 -> fp16 (RNE): 512000 quads, 2000 blocks ----
__global__ __launch_bounds__(256)
void cvt_table_f16(const float* __restrict__ t, _Float16* __restrict__ o) {
    const size_t i = (size_t)blockIdx.x * 256 + threadIdx.x;  // one quad each
    v4f v = *reinterpret_cast<const v4f*>(t + i * 4);
    _Float16 r[4];
    r[0] = (_Float16)v.x; r[1] = (_Float16)v.y;
    r[2] = (_Float16)v.z; r[3] = (_Float16)v.w;
    *reinterpret_cast<ushort4*>(o + i * 4) = *reinterpret_cast<ushort4*>(r);
}

// ---- main: one wave per row, lane l owns dims [4l, 4l+4) ----
__global__ __launch_bounds__(256)
void char2vec_row(const int* __restrict__ x,
                  const _Float16* __restrict__ tb,
                  float* __restrict__ out) {
    const int wave = threadIdx.x >> 6;
    const int lane = threadIdx.x & 63;
    const int row  = blockIdx.x * 4 + wave;
    const int d    = lane * 4;

    // 10 wave-uniform indices via 5 broadcast int2 loads (row*40 is 8-B aligned).
    const int2* __restrict__ xi = reinterpret_cast<const int2*>(x + row * 10);
    int2 p0 = xi[0], p1 = xi[1], p2 = xi[2], p3 = xi[3], p4 = xi[4];
    int idx[10] = {p0.x, p0.y, p1.x, p1.y, p2.x,
                   p2.y, p3.x, p3.y, p4.x, p4.y};

    // 10 independent 8-B gathers; each instr reads 512 B contiguous (4 lines).
    h4 v[10];
#pragma unroll
    for (int c = 0; c < 10; ++c)
        v[c] = *reinterpret_cast<const h4*>(tb + (size_t)idx[c] * TABLE_D + d);

    const float w[10] = {10.f / 55.f, 9.f / 55.f, 8.f / 55.f, 7.f / 55.f,
                         6.f / 55.f,  5.f / 55.f, 4.f / 55.f, 3.f / 55.f,
                         2.f / 55.f,  1.f / 55.f};

    v4f acc = (v4f)0.0f;
#pragma unroll
    for (int c = 0; c < 10; ++c) {
        acc.x = fmaf((float)v[c][0], w[c], acc.x);
        acc.y = fmaf((float)v[c][1], w[c], acc.y);
        acc.z = fmaf((float)v[c][2], w[c], acc.z);
        acc.w = fmaf((float)v[c][3], w[c], acc.w);
    }

    // One fully contiguous 1-KB store per row (wave-wide dwordx4).
    __builtin_nontemporal_store(
        acc, reinterpret_cast<v4f*>(out + (size_t)row * 256 + d));
}

// ---- fp32 fallback (R2 kernel) if ws too small ----
__global__ __launch_bounds__(256)
void char2vec_sliced2(const int* __restrict__ x,
                      const float* __restrict__ table,
                      float* __restrict__ out) {
    const int slice = blockIdx.x & 7;
    const int rgrp  = blockIdx.x >> 3;
    const int wave  = threadIdx.x >> 6;
    const int lane  = threadIdx.x & 63;

    const int row0 = rgrp * 64 + wave * 16 + (lane >> 3) * 2;
    const int row1 = row0 + 1;
    const int d    = slice * 32 + (lane & 7) * 4;

    const int2* __restrict__ xa = reinterpret_cast<const int2*>(x + row0 * 10);
    const int2* __restrict__ xb = reinterpret_cast<const int2*>(x + row1 * 10);
    int2 pa[5], pb[5];
#pragma unroll
    for (int i = 0; i < 5; ++i) pa[i] = xa[i];
#pragma unroll
    for (int i = 0; i < 5; ++i) pb[i] = xb[i];

    int ia[10], ib[10];
#pragma unroll
    for (int i = 0; i < 5; ++i) {
        ia[2 * i] = pa[i].x; ia[2 * i + 1] = pa[i].y;
        ib[2 * i] = pb[i].x; ib[2 * i + 1] = pb[i].y;
    }

    v4f va[10], vb[10];
#pragma unroll
    for (int c = 0; c < 10; ++c)
        va[c] = *reinterpret_cast<const v4f*>(table + (size_t)ia[c] * TABLE_D + d);
#pragma unroll
    for (int c = 0; c < 10; ++c)
        vb[c] = *reinterpret_cast<const v4f*>(table + (size_t)ib[c] * TABLE_D + d);

    const float w[10] = {10.f / 55.f, 9.f / 55.f, 8.f / 55.f, 7.f / 55.f,
                         6.f / 55.f,  5.f / 55.f, 4.f / 55.f, 3.f / 55.f,
                         2.f / 55.f,  1.f / 55.f};

    v4f acc0 = (v4f)0.0f, acc1 = (v4f)0.0f;
#pragma unroll
    for (int c = 0; c < 10; ++c) {
        acc0 += va[c] * w[c];
        acc1 += vb[c] * w[c];
    }

    __builtin_nontemporal_store(
        acc0, reinterpret_cast<v4f*>(out + (size_t)row0 * 256 + d));
    __builtin_nontemporal_store(
        acc1, reinterpret_cast<v4f*>(out + (size_t)row1 * 256 + d));
}

extern "C" void kernel_launch(void* const* d_in, const int* in_sizes, int n_in,
                              void* d_out, int out_size, void* d_ws, size_t ws_size,
                              hipStream_t stream) {
    const int*   x     = (const int*)d_in[0];
    const float* table = (const float*)d_in[1];
    float*       out   = (float*)d_out;

    const size_t f16_bytes = (size_t)TABLE_ROWS * TABLE_D * sizeof(_Float16);

    if (ws_size >= f16_bytes) {
        _Float16* tb = (_Float16*)d_ws;
        const int cvt_blocks = (TABLE_ROWS * TABLE_D / 4) / 256;   // 2000
        cvt_table_f16<<<cvt_blocks, 256, 0, stream>>>(table, tb);
        const int blocks = ROWS_TOTAL / 4;                          // 16384
        char2vec_row<<<blocks, 256, 0, stream>>>(x, tb, out);
    } else {
        const int blocks = (ROWS_TOTAL / 64) * 8;                   // 8192
        char2vec_sliced2<<<blocks, 256, 0, stream>>>(x, table, out);
    }
}

// Round 8
// 38.539 us; speedup vs baseline: 1.0464x; 1.0379x over previous
//
#include <hip/hip_runtime.h>
#include <hip/hip_bf16.h>

// out[t,f,d] = sum_{c=0..9} table[x[t,f,c], d] * w[c],  w[c] = (10-c)/55
// x: (1024,64,10) int32; table: (8000,256) f32; out: (1024,64,256) f32
//
// R7: single-variable experiment. R1-R6 falsified every gather-side model
// (MLP, bytes, line count, lane-requests, slicing/residency) -- main kernel
// pinned at ~32 us throughout. The one never-varied factor: ALL stores were
// nontemporal. Observed effective write rate 64 MB / 32 us ~= 2 TB/s vs the
// harness fill kernels' 6.3+ TB/s with regular stores. Hypothesis: gfx950 nt
// (no-allocate) stores bypass L2 write aggregation and sink at ~1/3 rate,
// making the write stream the binding resource in every sliced variant.
// This kernel == R2 exactly (fp32 table, XCD d-slicing, 2 rows/thread,
// single dispatch) with REGULAR stores. Predicted 15-22 us if theory holds.

#define ROWS_TOTAL (1024 * 64)   // 65536 rows of 256 floats
#define TABLE_D    256

typedef float v4f __attribute__((ext_vector_type(4)));

__global__ __launch_bounds__(256)
void char2vec_sliced2r(const int* __restrict__ x,
                       const float* __restrict__ table,
                       float* __restrict__ out) {
    const int slice = blockIdx.x & 7;        // -> XCD (round-robin)
    const int rgrp  = blockIdx.x >> 3;       // row-group of 64 rows
    const int wave  = threadIdx.x >> 6;
    const int lane  = threadIdx.x & 63;

    // Each 8-lane group handles 2 consecutive rows; 8 groups/wave, 4 waves.
    const int row0 = rgrp * 64 + wave * 16 + (lane >> 3) * 2;
    const int row1 = row0 + 1;
    const int d    = slice * 32 + (lane & 7) * 4;   // float4 within slice

    // 20 indices (2 rows x 10), via int2 (row*40 is always 8B-aligned).
    const int2* __restrict__ xa = reinterpret_cast<const int2*>(x + row0 * 10);
    const int2* __restrict__ xb = reinterpret_cast<const int2*>(x + row1 * 10);
    int2 pa[5], pb[5];
#pragma unroll
    for (int i = 0; i < 5; ++i) pa[i] = xa[i];
#pragma unroll
    for (int i = 0; i < 5; ++i) pb[i] = xb[i];

    int ia[10], ib[10];
#pragma unroll
    for (int i = 0; i < 5; ++i) {
        ia[2 * i] = pa[i].x; ia[2 * i + 1] = pa[i].y;
        ib[2 * i] = pb[i].x; ib[2 * i + 1] = pb[i].y;
    }

    // 20 independent float4 gathers, all in flight together.
    v4f va[10], vb[10];
#pragma unroll
    for (int c = 0; c < 10; ++c)
        va[c] = *reinterpret_cast<const v4f*>(table + (size_t)ia[c] * TABLE_D + d);
#pragma unroll
    for (int c = 0; c < 10; ++c)
        vb[c] = *reinterpret_cast<const v4f*>(table + (size_t)ib[c] * TABLE_D + d);

    const float w[10] = {10.f / 55.f, 9.f / 55.f, 8.f / 55.f, 7.f / 55.f,
                         6.f / 55.f,  5.f / 55.f, 4.f / 55.f, 3.f / 55.f,
                         2.f / 55.f,  1.f / 55.f};

    v4f acc0 = (v4f)0.0f, acc1 = (v4f)0.0f;
#pragma unroll
    for (int c = 0; c < 10; ++c) {
        acc0 += va[c] * w[c];
        acc1 += vb[c] * w[c];
    }

    // REGULAR stores (the single change vs R2): let the write stream
    // aggregate in L2 write-back like the 6.3-TB/s fill kernels do.
    *reinterpret_cast<v4f*>(out + (size_t)row0 * 256 + d) = acc0;
    *reinterpret_cast<v4f*>(out + (size_t)row1 * 256 + d) = acc1;
}

extern "C" void kernel_launch(void* const* d_in, const int* in_sizes, int n_in,
                              void* d_out, int out_size, void* d_ws, size_t ws_size,
                              hipStream_t stream) {
    const int*   x     = (const int*)d_in[0];
    const float* table = (const float*)d_in[1];
    float*       out   = (float*)d_out;

    // 64 rows per block, 8 d-slices: 65536/64 * 8 = 8192 blocks.
    const int blocks = (ROWS_TOTAL / 64) * 8;
    char2vec_sliced2r<<<blocks, 256, 0, stream>>>(x, table, out);
}

// Round 9
// 31.597 us; speedup vs baseline: 1.2762x; 1.2197x over previous
//
#include <hip/hip_runtime.h>
#include <hip/hip_fp16.h>

// out[t,f,d] = sum_{c=0..9} table[x[t,f,c], d] * w[c],  w[c] = (10-c)/55
// x: (1024,64,10) int32; table: (8000,256) f32; out: (1024,64,256) f32
//
// R9 theory: bottleneck = VMEM wave-instruction issue rate (~16 cyc/instr/CU
// at the texture addresser). Every prior round issued >=27 VMEM instrs per
// 2 output rows -> invariant ~32 us wall (VALUBusy 17%, HBM 25%: both idle).
// This kernel issues 13 per 2 rows:
//   1 idx dword load (+10 __shfl broadcasts on the LDS pipe, not TA)
//  10 fp16 gathers: half-wave covers a FULL 512-B fp16 row at 16 B/lane
//   2 contiguous dwordx4 nt stores
// The fp16 table (4 MB, in d_ws) is PERMUTED so no shuffle is needed at the
// store: chunk m (16 B = 8 halfs) of a row = dims [4m,4m+4) U [128+4m,+4).
// Lane m's acc then stores directly to out dims 4m (lo) and 128+4m (hi).
// cvt uses nontemporal stores -> no dirty-L2 cross-XCD pollution (the
// R4-R7 confound). fp16 err (~2.5e-3) well under threshold 0.03875; fp8
// would fail accuracy, and 16 B/lane is the VMEM width cap -> this is the
// instruction-minimal structure.

#define ROWS_TOTAL (1024 * 64)
#define TROWS 8000
#define TD 256

typedef float v4f __attribute__((ext_vector_type(4)));
typedef _Float16 h8 __attribute__((ext_vector_type(8)));

// ---- cvt: fp32 table -> permuted fp16 table in ws ----
// tid = row*32 + m; writes 16 B chunk m = dims [4m,4m+4) and [128+4m,+4).
__global__ __launch_bounds__(256)
void cvt_perm(const float* __restrict__ t, _Float16* __restrict__ o) {
    const int tid = blockIdx.x * 256 + threadIdx.x;   // 0 .. 256000
    const int row = tid >> 5;
    const int m   = tid & 31;
    const float* src = t + (size_t)row * TD + 4 * m;
    v4f a = *reinterpret_cast<const v4f*>(src);        // dims [4m, 4m+4)
    v4f b = *reinterpret_cast<const v4f*>(src + 128);  // dims [128+4m, +4)
    h8 r;
    r[0] = (_Float16)a.x; r[1] = (_Float16)a.y;
    r[2] = (_Float16)a.z; r[3] = (_Float16)a.w;
    r[4] = (_Float16)b.x; r[5] = (_Float16)b.y;
    r[6] = (_Float16)b.z; r[7] = (_Float16)b.w;
    __builtin_nontemporal_store(r, reinterpret_cast<h8*>(o + (size_t)tid * 8));
}

// ---- main: 2 rows per wave (one per half-wave), 13 VMEM instrs/wave ----
__global__ __launch_bounds__(256)
void char2vec_hw(const int* __restrict__ x,
                 const _Float16* __restrict__ tb,
                 float* __restrict__ out) {
    const int l    = threadIdx.x & 63;
    const int wave = threadIdx.x >> 6;
    const int row0 = (blockIdx.x * 4 + wave) * 2;   // even row pair
    const int half = l >> 5;                        // 0 -> row0, 1 -> row0+1
    const int m    = l & 31;
    const int row  = row0 + half;

    // One dword load covers all 20 indices of the row pair (lanes 20-63
    // redundantly re-read the last one -> same cache line, no divergence).
    const int t = x[row0 * 10 + (l < 20 ? l : 19)];

    // Broadcast via LDS-pipe shuffles: gather c of this half uses lane half*10+c.
    int idx[10];
#pragma unroll
    for (int c = 0; c < 10; ++c) idx[c] = __shfl(t, half * 10 + c);

    // 10 gathers; each half-wave reads one full permuted fp16 row (512 B
    // contiguous, 16 B/lane). All 10 independent, in flight together.
    h8 v[10];
#pragma unroll
    for (int c = 0; c < 10; ++c)
        v[c] = *reinterpret_cast<const h8*>(tb + (size_t)idx[c] * TD + m * 8);

    const float w[10] = {10.f / 55.f, 9.f / 55.f, 8.f / 55.f, 7.f / 55.f,
                         6.f / 55.f,  5.f / 55.f, 4.f / 55.f, 3.f / 55.f,
                         2.f / 55.f,  1.f / 55.f};

    float acc[8] = {0, 0, 0, 0, 0, 0, 0, 0};
#pragma unroll
    for (int c = 0; c < 10; ++c) {
#pragma unroll
        for (int e = 0; e < 8; ++e)
            acc[e] = fmaf((float)v[c][e], w[c], acc[e]);
    }

    // Permuted layout -> direct contiguous stores, no cross-lane traffic:
    // lanes of each half-wave cover dims [0,128) then [128,256) of their row.
    v4f lo = {acc[0], acc[1], acc[2], acc[3]};   // dims [4m, 4m+4)
    v4f hi = {acc[4], acc[5], acc[6], acc[7]};   // dims [128+4m, +4)
    float* orow = out + (size_t)row * TD;
    __builtin_nontemporal_store(lo, reinterpret_cast<v4f*>(orow + 4 * m));
    __builtin_nontemporal_store(hi, reinterpret_cast<v4f*>(orow + 128 + 4 * m));
}

// ---- fp32 fallback (R3 kernel) if ws too small ----
__global__ __launch_bounds__(256)
void char2vec_sliced2(const int* __restrict__ x,
                      const float* __restrict__ table,
                      float* __restrict__ out) {
    const int slice = blockIdx.x & 7;
    const int rgrp  = blockIdx.x >> 3;
    const int wave  = threadIdx.x >> 6;
    const int lane  = threadIdx.x & 63;

    const int row0 = rgrp * 64 + wave * 16 + (lane >> 3) * 2;
    const int row1 = row0 + 1;
    const int d    = slice * 32 + (lane & 7) * 4;

    const int2* __restrict__ xa = reinterpret_cast<const int2*>(x + row0 * 10);
    const int2* __restrict__ xb = reinterpret_cast<const int2*>(x + row1 * 10);
    int2 pa[5], pb[5];
#pragma unroll
    for (int i = 0; i < 5; ++i) pa[i] = xa[i];
#pragma unroll
    for (int i = 0; i < 5; ++i) pb[i] = xb[i];

    int ia[10], ib[10];
#pragma unroll
    for (int i = 0; i < 5; ++i) {
        ia[2 * i] = pa[i].x; ia[2 * i + 1] = pa[i].y;
        ib[2 * i] = pb[i].x; ib[2 * i + 1] = pb[i].y;
    }

    v4f va[10], vb[10];
#pragma unroll
    for (int c = 0; c < 10; ++c)
        va[c] = *reinterpret_cast<const v4f*>(table + (size_t)ia[c] * TD + d);
#pragma unroll
    for (int c = 0; c < 10; ++c)
        vb[c] = *reinterpret_cast<const v4f*>(table + (size_t)ib[c] * TD + d);

    const float w[10] = {10.f / 55.f, 9.f / 55.f, 8.f / 55.f, 7.f / 55.f,
                         6.f / 55.f,  5.f / 55.f, 4.f / 55.f, 3.f / 55.f,
                         2.f / 55.f,  1.f / 55.f};

    v4f acc0 = (v4f)0.0f, acc1 = (v4f)0.0f;
#pragma unroll
    for (int c = 0; c < 10; ++c) {
        acc0 += va[c] * w[c];
        acc1 += vb[c] * w[c];
    }

    __builtin_nontemporal_store(
        acc0, reinterpret_cast<v4f*>(out + (size_t)row0 * TD + d));
    __builtin_nontemporal_store(
        acc1, reinterpret_cast<v4f*>(out + (size_t)row1 * TD + d));
}

extern "C" void kernel_launch(void* const* d_in, const int* in_sizes, int n_in,
                              void* d_out, int out_size, void* d_ws, size_t ws_size,
                              hipStream_t stream) {
    const int*   x     = (const int*)d_in[0];
    const float* table = (const float*)d_in[1];
    float*       out   = (float*)d_out;

    const size_t f16_bytes = (size_t)TROWS * TD * sizeof(_Float16);

    if (ws_size >= f16_bytes) {
        _Float16* tb = (_Float16*)d_ws;
        // 8000 rows * 32 chunks / 256 threads = 1000 blocks
        cvt_perm<<<(TROWS * 32) / 256, 256, 0, stream>>>(table, tb);
        // 2 rows/wave * 4 waves/block = 8 rows/block -> 8192 blocks
        char2vec_hw<<<ROWS_TOTAL / 8, 256, 0, stream>>>(x, tb, out);
    } else {
        const int blocks = (ROWS_TOTAL / 64) * 8;   // 8192
        char2vec_sliced2<<<blocks, 256, 0, stream>>>(x, table, out);
    }
}

// Round 10
// 29.590 us; speedup vs baseline: 1.3628x; 1.0679x over previous
//
#include <hip/hip_runtime.h>
#include <hip/hip_fp16.h>

// out[t,f,d] = sum_{c=0..9} table[x[t,f,c], d] * w[c],  w[c] = (10-c)/55
// x: (1024,64,10) int32; table: (8000,256) f32; out: (1024,64,256) f32
//
// R10: R9's 13-VMEM-instr structure + TWO changes aimed at the write path:
//  (1) REGULAR stores (not nontemporal) in contiguous 256-B runs -> the
//      64-MB write stream aggregates in L2 write-back like the 6.3-TB/s
//      fill kernels (all prior nt-store kernels sank writes at ~2.4 TB/s).
//  (2) 2 d-slices (slice = blockIdx&1 -> XCD parity): per-XCD permuted-fp16
//      table slice is 2 MB, leaving 2 MB of the 4-MB XCD L2 for the write
//      stream, removing R8's write-allocate thrash confound (8-MB fp32
//      table). Table lines are re-referenced ~80x more often than the
//      streaming write lines -> slice stays resident.
// Structure per wave (4 half-rows = 2 row-equivalents, 13 VMEM instrs):
//   1 idx dword load (lanes 0..39; +__shfl broadcasts, LDS pipe)
//  10 fp16 gathers: quarter-wave reads one 256-B permuted row-slice
//   2 contiguous dwordx4 stores (each instr: 4x 256-B runs)
// Permuted slice layout: chunk i (16 B) of (row,s) = dims [128s+4i,+4) U
// [128s+64+4i,+4), so FMA results store directly with no cross-lane moves.
// fp16 err ~2.5e-3 << threshold 0.03875. Fallback: R3 fp32 kernel.

#define ROWS_TOTAL (1024 * 64)
#define TROWS 8000
#define TD 256

typedef float v4f __attribute__((ext_vector_type(4)));
typedef _Float16 h8 __attribute__((ext_vector_type(8)));

// ---- cvt: fp32 table -> 2-slice permuted fp16 in ws ----
// tid = row*32 + s*16 + i  ->  16-B chunk = dims [128s+4i,+4) U [128s+64+4i,+4)
__global__ __launch_bounds__(256)
void cvt_perm2(const float* __restrict__ t, _Float16* __restrict__ o) {
    const int tid = blockIdx.x * 256 + threadIdx.x;   // 0 .. 256000
    const int row = tid >> 5;
    const int s   = (tid >> 4) & 1;
    const int i   = tid & 15;
    const float* src = t + (size_t)row * TD + s * 128 + 4 * i;
    v4f a = *reinterpret_cast<const v4f*>(src);        // dims 128s+4i ..
    v4f b = *reinterpret_cast<const v4f*>(src + 64);   // dims 128s+64+4i ..
    h8 r;
    r[0] = (_Float16)a.x; r[1] = (_Float16)a.y;
    r[2] = (_Float16)a.z; r[3] = (_Float16)a.w;
    r[4] = (_Float16)b.x; r[5] = (_Float16)b.y;
    r[6] = (_Float16)b.z; r[7] = (_Float16)b.w;
    __builtin_nontemporal_store(r, reinterpret_cast<h8*>(o + (size_t)tid * 8));
}

// ---- main: 4 rows x 1 half-slice per wave; 13 VMEM instrs ----
__global__ __launch_bounds__(256)
void char2vec_w2(const int* __restrict__ x,
                 const _Float16* __restrict__ tb,
                 float* __restrict__ out) {
    const int l  = threadIdx.x & 63;
    const int wv = threadIdx.x >> 6;
    const int q  = l >> 4;                 // quarter -> row offset
    const int i  = l & 15;                 // 16-B chunk within half-slice

    const int s       = blockIdx.x & 1;    // d-half; blockIdx%8 -> XCD parity
    const int rowbase = (blockIdx.x >> 1) * 16 + wv * 4;
    const int row     = rowbase + q;

    // 40 indices for the 4-row group in lanes 0..39 (one dword instr).
    const int t = x[rowbase * 10 + (l < 40 ? l : 39)];

    int idx[10];
#pragma unroll
    for (int c = 0; c < 10; ++c) idx[c] = __shfl(t, q * 10 + c);

    // 10 independent gathers; quarter-wave reads a 256-B permuted row-slice.
    h8 v[10];
#pragma unroll
    for (int c = 0; c < 10; ++c)
        v[c] = *reinterpret_cast<const h8*>(
            tb + (size_t)idx[c] * TD + s * 128 + i * 8);

    const float w[10] = {10.f / 55.f, 9.f / 55.f, 8.f / 55.f, 7.f / 55.f,
                         6.f / 55.f,  5.f / 55.f, 4.f / 55.f, 3.f / 55.f,
                         2.f / 55.f,  1.f / 55.f};

    float acc[8] = {0, 0, 0, 0, 0, 0, 0, 0};
#pragma unroll
    for (int c = 0; c < 10; ++c) {
#pragma unroll
        for (int e = 0; e < 8; ++e)
            acc[e] = fmaf((float)v[c][e], w[c], acc[e]);
    }

    // REGULAR stores; each instr writes 4 contiguous 256-B runs.
    v4f lo = {acc[0], acc[1], acc[2], acc[3]};   // dims 128s+4i ..
    v4f hi = {acc[4], acc[5], acc[6], acc[7]};   // dims 128s+64+4i ..
    float* orow = out + (size_t)row * TD + s * 128;
    *reinterpret_cast<v4f*>(orow + 4 * i)      = lo;
    *reinterpret_cast<v4f*>(orow + 64 + 4 * i) = hi;
}

// ---- fp32 fallback (R3 kernel) if ws too small ----
__global__ __launch_bounds__(256)
void char2vec_sliced2(const int* __restrict__ x,
                      const float* __restrict__ table,
                      float* __restrict__ out) {
    const int slice = blockIdx.x & 7;
    const int rgrp  = blockIdx.x >> 3;
    const int wave  = threadIdx.x >> 6;
    const int lane  = threadIdx.x & 63;

    const int row0 = rgrp * 64 + wave * 16 + (lane >> 3) * 2;
    const int row1 = row0 + 1;
    const int d    = slice * 32 + (lane & 7) * 4;

    const int2* __restrict__ xa = reinterpret_cast<const int2*>(x + row0 * 10);
    const int2* __restrict__ xb = reinterpret_cast<const int2*>(x + row1 * 10);
    int2 pa[5], pb[5];
#pragma unroll
    for (int i = 0; i < 5; ++i) pa[i] = xa[i];
#pragma unroll
    for (int i = 0; i < 5; ++i) pb[i] = xb[i];

    int ia[10], ib[10];
#pragma unroll
    for (int i = 0; i < 5; ++i) {
        ia[2 * i] = pa[i].x; ia[2 * i + 1] = pa[i].y;
        ib[2 * i] = pb[i].x; ib[2 * i + 1] = pb[i].y;
    }

    v4f va[10], vb[10];
#pragma unroll
    for (int c = 0; c < 10; ++c)
        va[c] = *reinterpret_cast<const v4f*>(table + (size_t)ia[c] * TD + d);
#pragma unroll
    for (int c = 0; c < 10; ++c)
        vb[c] = *reinterpret_cast<const v4f*>(table + (size_t)ib[c] * TD + d);

    const float w[10] = {10.f / 55.f, 9.f / 55.f, 8.f / 55.f, 7.f / 55.f,
                         6.f / 55.f,  5.f / 55.f, 4.f / 55.f, 3.f / 55.f,
                         2.f / 55.f,  1.f / 55.f};

    v4f acc0 = (v4f)0.0f, acc1 = (v4f)0.0f;
#pragma unroll
    for (int c = 0; c < 10; ++c) {
        acc0 += va[c] * w[c];
        acc1 += vb[c] * w[c];
    }

    __builtin_nontemporal_store(
        acc0, reinterpret_cast<v4f*>(out + (size_t)row0 * TD + d));
    __builtin_nontemporal_store(
        acc1, reinterpret_cast<v4f*>(out + (size_t)row1 * TD + d));
}

extern "C" void kernel_launch(void* const* d_in, const int* in_sizes, int n_in,
                              void* d_out, int out_size, void* d_ws, size_t ws_size,
                              hipStream_t stream) {
    const int*   x     = (const int*)d_in[0];
    const float* table = (const float*)d_in[1];
    float*       out   = (float*)d_out;

    const size_t f16_bytes = (size_t)TROWS * TD * sizeof(_Float16);

    if (ws_size >= f16_bytes) {
        _Float16* tb = (_Float16*)d_ws;
        // 8000 rows * 32 chunks / 256 = 1000 blocks
        cvt_perm2<<<(TROWS * 32) / 256, 256, 0, stream>>>(table, tb);
        // 16 rows x 2 slices per block-pair: 65536/16*2 = 8192 blocks
        char2vec_w2<<<(ROWS_TOTAL / 16) * 2, 256, 0, stream>>>(x, tb, out);
    } else {
        const int blocks = (ROWS_TOTAL / 64) * 8;   // 8192
        char2vec_sliced2<<<blocks, 256, 0, stream>>>(x, table, out);
    }
}